// Round 8
// baseline (216.851 us; speedup 1.0000x reference)
//
#include <hip/hip_runtime.h>
#include <cmath>

#define N_NODES 50000
#define N_EDGES 800000
#define D 64
#define N_REL 8

#define NODES_PER_BLK 32
#define CSTRIDE 132                 // 128 + 4 pad; float4 rows stay 16B-aligned
#define NB_SCAN 196                 // ceil(50000/256)
#define TN 16                       // nodes per block in tables_kernel

// ---------------------------------------------------------------------------
// K0: w[r*128 + j] = sum_k W_r[r][j][k]
// ---------------------------------------------------------------------------
__global__ void wprep_kernel(const float* __restrict__ W_r, float* __restrict__ w) {
    int t = blockIdx.x * blockDim.x + threadIdx.x;
    if (t >= N_REL * 2 * D) return;
    const float* p = W_r + (size_t)t * D;
    float s = 0.0f;
#pragma unroll
    for (int k = 0; k < D; ++k) s += p[k];
    w[t] = s;
}

// ---------------------------------------------------------------------------
// K1: logit tables as a tall-skinny GEMM: T[n][q] = <x[n], w_row_q>.
// ---------------------------------------------------------------------------
__global__ __launch_bounds__(256) void tables_kernel(
    const float* __restrict__ x, const float* __restrict__ w,
    float* __restrict__ Dn, float* __restrict__ Sr)
{
    __shared__ float xs[TN][68];
    __shared__ float ws[16][68];

    int tid = threadIdx.x;
    int n0  = blockIdx.x * TN;

    for (int i = tid; i < 16 * 64; i += 256)
        ws[i >> 6][i & 63] = w[i];
    for (int i = tid; i < TN * 64; i += 256) {
        int n = n0 + (i >> 6);
        xs[i >> 6][i & 63] = (n < N_NODES) ? x[(size_t)n * D + (i & 63)] : 0.f;
    }
    __syncthreads();

    int q = tid & 15, nl = tid >> 4;
    float acc = 0.f;
#pragma unroll
    for (int k = 0; k < 64; k += 4) {
        float4 a = *(const float4*)&xs[nl][k];
        float4 b = *(const float4*)&ws[q][k];
        acc += a.x * b.x + a.y * b.y + a.z * b.z + a.w * b.w;
    }
    int n = n0 + nl;
    if (n < N_NODES) {
        int r = q >> 1;
        if ((q & 1) == 0) Dn[n * 8 + r] = acc;
        else              Sr[n * 8 + r] = acc;
    }
}

// ---------------------------------------------------------------------------
// K2: degree histogram that keeps the rank (only atomic pass).
// ---------------------------------------------------------------------------
__global__ void rank_kernel(const int* __restrict__ dst,
                            int* __restrict__ cnt, int* __restrict__ rank) {
    int e = blockIdx.x * blockDim.x + threadIdx.x;
    if (e < N_EDGES) rank[e] = atomicAdd(&cnt[dst[e]], 1);
}

// ---------------------------------------------------------------------------
// K3a/b/c: exclusive scan of cnt -> row_ptr
// ---------------------------------------------------------------------------
__global__ __launch_bounds__(256) void scanA(const int* __restrict__ cnt,
                                             int* __restrict__ excl,
                                             int* __restrict__ partial) {
    __shared__ int s[256];
    int t = threadIdx.x;
    int i = blockIdx.x * 256 + t;
    int v = (i < N_NODES) ? cnt[i] : 0;
    s[t] = v;
    __syncthreads();
    for (int off = 1; off < 256; off <<= 1) {
        int add = (t >= off) ? s[t - off] : 0;
        __syncthreads();
        s[t] += add;
        __syncthreads();
    }
    if (i < N_NODES) excl[i] = s[t] - v;
    if (t == 255) partial[blockIdx.x] = s[255];
}

__global__ __launch_bounds__(256) void scanB(int* __restrict__ partial) {
    __shared__ int s[256];
    int t = threadIdx.x;
    int v = (t < NB_SCAN) ? partial[t] : 0;
    s[t] = v;
    __syncthreads();
    for (int off = 1; off < 256; off <<= 1) {
        int add = (t >= off) ? s[t - off] : 0;
        __syncthreads();
        s[t] += add;
        __syncthreads();
    }
    if (t < NB_SCAN) partial[t] = s[t] - v;
}

__global__ __launch_bounds__(256) void scanC(const int* __restrict__ excl,
                                             const int* __restrict__ partial,
                                             int* __restrict__ row_ptr) {
    int i = blockIdx.x * 256 + threadIdx.x;
    if (i < N_NODES) row_ptr[i] = excl[i] + partial[i >> 8];
    if (i == N_NODES) row_ptr[N_NODES] = N_EDGES;
}

// ---------------------------------------------------------------------------
// K4: scatter edges into CSR order with gate precomputed. No atomics:
// pos = row_ptr[dst] + rank[e]. epack[pos] = (gate, src-bits).
// ---------------------------------------------------------------------------
__global__ void scatter_kernel(const int* __restrict__ src, const int* __restrict__ dst,
                               const int* __restrict__ rel, const int* __restrict__ rank,
                               const int* __restrict__ row_ptr,
                               const float* __restrict__ Dn, const float* __restrict__ Sr,
                               float2* __restrict__ epack) {
    int e = blockIdx.x * blockDim.x + threadIdx.x;
    if (e >= N_EDGES) return;
    int s = src[e], d = dst[e], r = rel[e];
    float logit = Dn[d * 8 + r] + Sr[s * 8 + r];
    float gate = 1.0f / (1.0f + __expf(-logit));
    int pos = row_ptr[d] + rank[e];
    float2 v; v.x = gate; v.y = __int_as_float(s);
    epack[pos] = v;
}

// ---------------------------------------------------------------------------
// K5: aggregation. Wave = 4 edge-slots x 16 lanes; each lane owns a float4
// quarter-row (dims 4q..4q+3). Per 4 edges: 1 dwordx4 gather/lane (1KB/wave
// instr) + broadcast epack read + 4 FMAs — vs R7's 1 load + 2 shfl + 1 fma
// PER EDGE per lane. End-of-row shfl_xor(16,32) reduction, 16-lane float4
// store. 2x manual unroll for 2 gathers in flight.
// ---------------------------------------------------------------------------
__global__ __launch_bounds__(256) void agg_kernel(
    const float* __restrict__ x,
    const int*   __restrict__ row_ptr,
    const float2* __restrict__ epack,
    float* __restrict__ agg)           // (N_NODES, 64) normalized
{
    int n    = (blockIdx.x * blockDim.x + threadIdx.x) >> 6;
    int lane = threadIdx.x & 63;
    if (n >= N_NODES) return;

    int sub = lane >> 4;      // edge slot 0..3
    int q   = lane & 15;      // quarter-row: dims 4q..4q+3
    int beg = row_ptr[n], end = row_ptr[n + 1];

    float ax = 0.f, ay = 0.f, az = 0.f, aw = 0.f;

    for (int base = beg; base < end; base += 8) {
        int e0 = base + sub;
        int e1 = base + 4 + sub;
        float g0 = 0.f, g1 = 0.f;
        int   s0 = 0,   s1 = 0;
        if (e0 < end) { float2 v = epack[e0]; g0 = v.x; s0 = __float_as_int(v.y); }
        if (e1 < end) { float2 v = epack[e1]; g1 = v.x; s1 = __float_as_int(v.y); }
        float4 x0 = {0.f, 0.f, 0.f, 0.f}, x1 = {0.f, 0.f, 0.f, 0.f};
        if (e0 < end) x0 = *(const float4*)&x[(size_t)s0 * D + 4 * q];
        if (e1 < end) x1 = *(const float4*)&x[(size_t)s1 * D + 4 * q];
        ax += g0 * x0.x; ay += g0 * x0.y; az += g0 * x0.z; aw += g0 * x0.w;
        ax += g1 * x1.x; ay += g1 * x1.y; az += g1 * x1.z; aw += g1 * x1.w;
    }

    // reduce the 4 edge slots (lanes xor 16, xor 32)
#pragma unroll
    for (int off = 16; off <= 32; off <<= 1) {
        ax += __shfl_xor(ax, off, 64);
        ay += __shfl_xor(ay, off, 64);
        az += __shfl_xor(az, off, 64);
        aw += __shfl_xor(aw, off, 64);
    }

    if (sub == 0) {
        float inv = 1.0f / fmaxf((float)(end - beg), 1.0f);
        float4 r; r.x = ax * inv; r.y = ay * inv; r.z = az * inv; r.w = aw * inv;
        *(float4*)&agg[(size_t)n * D + 4 * q] = r;
    }
}

// ---------------------------------------------------------------------------
// K6: out = leaky_relu([x, agg] @ W_lin^T + b). Block = 256 thr, 32 nodes.
// ---------------------------------------------------------------------------
__global__ __launch_bounds__(256, 4) void lin_kernel(
    const float* __restrict__ x,
    const float* __restrict__ agg,
    const float* __restrict__ W_lin,
    const float* __restrict__ b_lin,
    float* __restrict__ out)
{
    __shared__ float c_lds[NODES_PER_BLK][CSTRIDE];
    __shared__ float W_lds[64][CSTRIDE];
    __shared__ float b_lds[64];

    int tid  = threadIdx.x;
    int wid  = tid >> 6;
    int lane = tid & 63;
    int n0   = blockIdx.x * NODES_PER_BLK;

    for (int i = tid; i < 64 * 128; i += 256)
        W_lds[i >> 7][i & 127] = W_lin[i];
    if (tid < 64) b_lds[tid] = b_lin[tid];

#pragma unroll
    for (int it = 0; it < NODES_PER_BLK / 4; ++it) {
        int nl = wid * (NODES_PER_BLK / 4) + it;
        int n  = n0 + nl;
        if (n < N_NODES) {
            c_lds[nl][lane]      = x[(size_t)n * D + lane];
            c_lds[nl][64 + lane] = agg[(size_t)n * D + lane];
        } else {
            c_lds[nl][lane] = 0.f;
            c_lds[nl][64 + lane] = 0.f;
        }
    }
    __syncthreads();

    int tx = tid & 15, ty = tid >> 4;
    float acc[2][4];
#pragma unroll
    for (int i = 0; i < 2; ++i)
#pragma unroll
        for (int jj = 0; jj < 4; ++jj) acc[i][jj] = b_lds[tx + 16 * jj];

#pragma unroll 2
    for (int k = 0; k < 128; k += 4) {
        float4 cv[2], wv[4];
        cv[0] = *(const float4*)&c_lds[ty][k];
        cv[1] = *(const float4*)&c_lds[ty + 16][k];
#pragma unroll
        for (int jj = 0; jj < 4; ++jj)
            wv[jj] = *(const float4*)&W_lds[tx + 16 * jj][k];
#pragma unroll
        for (int i = 0; i < 2; ++i)
#pragma unroll
            for (int jj = 0; jj < 4; ++jj)
                acc[i][jj] += cv[i].x * wv[jj].x + cv[i].y * wv[jj].y
                            + cv[i].z * wv[jj].z + cv[i].w * wv[jj].w;
    }

#pragma unroll
    for (int i = 0; i < 2; ++i) {
        int n = n0 + ty + 16 * i;
        if (n < N_NODES) {
#pragma unroll
            for (int jj = 0; jj < 4; ++jj) {
                float v = acc[i][jj];
                out[(size_t)n * D + tx + 16 * jj] = (v > 0.f) ? v : 0.01f * v;
            }
        }
    }
}

// ---------------------------------------------------------------------------
extern "C" void kernel_launch(void* const* d_in, const int* in_sizes, int n_in,
                              void* d_out, int out_size, void* d_ws, size_t ws_size,
                              hipStream_t stream) {
    const float* x     = (const float*)d_in[0];
    const int*   src   = (const int*)  d_in[1];
    const int*   dst   = (const int*)  d_in[2];
    const int*   rel   = (const int*)  d_in[3];
    const float* W_r   = (const float*)d_in[4];
    const float* W_lin = (const float*)d_in[5];
    const float* b_lin = (const float*)d_in[6];
    float* out = (float*)d_out;

    char* p = (char*)d_ws;
    float*  w       = (float*)p;                p += 4096;
    float*  Dn      = (float*)p;                p += (size_t)N_NODES * 8 * 4;   // 1.6 MB
    float*  Sr      = (float*)p;                p += (size_t)N_NODES * 8 * 4;   // 1.6 MB
    int*    cnt     = (int*)p;                  p += (size_t)N_NODES * 4;
    int*    excl    = (int*)p;                  p += (size_t)N_NODES * 4;
    int*    row_ptr = (int*)p;                  p += (size_t)(N_NODES + 64) * 4;
    int*    partial = (int*)p;                  p += 1024;
    int*    rank    = (int*)p;                  p += (size_t)N_EDGES * 4;       // 3.2 MB
    float*  agg     = (float*)p;                p += (size_t)N_NODES * D * 4;   // 12.8 MB
    float2* epack   = (float2*)p;               p += (size_t)N_EDGES * 8;       // 6.4 MB

    hipMemsetAsync(cnt, 0, (size_t)N_NODES * sizeof(int), stream);

    wprep_kernel<<<4, 256, 0, stream>>>(W_r, w);
    tables_kernel<<<(N_NODES + TN - 1) / TN, 256, 0, stream>>>(x, w, Dn, Sr);
    rank_kernel<<<(N_EDGES + 255) / 256, 256, 0, stream>>>(dst, cnt, rank);
    scanA<<<NB_SCAN, 256, 0, stream>>>(cnt, excl, partial);
    scanB<<<1, 256, 0, stream>>>(partial);
    scanC<<<NB_SCAN, 256, 0, stream>>>(excl, partial, row_ptr);
    scatter_kernel<<<(N_EDGES + 255) / 256, 256, 0, stream>>>(src, dst, rel, rank, row_ptr,
                                                              Dn, Sr, epack);
    agg_kernel<<<(N_NODES * 64 + 255) / 256, 256, 0, stream>>>(x, row_ptr, epack, agg);
    lin_kernel<<<(N_NODES + NODES_PER_BLK - 1) / NODES_PER_BLK, 256, 0, stream>>>(
        x, agg, W_lin, b_lin, out);
}

// Round 9
// 216.833 us; speedup vs baseline: 1.0001x; 1.0001x over previous
//
#include <hip/hip_runtime.h>
#include <cmath>

#define N_NODES 50000
#define N_EDGES 800000
#define D 64
#define N_REL 8

#define NODES_PER_BLK 32
#define CSTRIDE 132                 // 128 + 4 pad; float4 rows stay 16B-aligned
#define NB_SCAN 196                 // ceil(50000/256)
#define TN 16                       // nodes per block in tables_kernel

// float -> bf16 bits, round-to-nearest-even
static __device__ __forceinline__ unsigned short f2bf(float f) {
    unsigned u = __float_as_uint(f);
    return (unsigned short)((u + 0x7FFFu + ((u >> 16) & 1u)) >> 16);
}

// ---------------------------------------------------------------------------
// K0: w[r*128 + j] = sum_k W_r[r][j][k]
// ---------------------------------------------------------------------------
__global__ void wprep_kernel(const float* __restrict__ W_r, float* __restrict__ w) {
    int t = blockIdx.x * blockDim.x + threadIdx.x;
    if (t >= N_REL * 2 * D) return;
    const float* p = W_r + (size_t)t * D;
    float s = 0.0f;
#pragma unroll
    for (int k = 0; k < D; ++k) s += p[k];
    w[t] = s;
}

// ---------------------------------------------------------------------------
// K1: logit tables (tall-skinny GEMM) + side-product: x_bf16 for the agg
// gather path (x is already staged in LDS here — conversion is free BW-wise).
// ---------------------------------------------------------------------------
__global__ __launch_bounds__(256) void tables_kernel(
    const float* __restrict__ x, const float* __restrict__ w,
    float* __restrict__ Dn, float* __restrict__ Sr,
    unsigned short* __restrict__ xb)
{
    __shared__ float xs[TN][68];
    __shared__ float ws[16][68];

    int tid = threadIdx.x;
    int n0  = blockIdx.x * TN;

    for (int i = tid; i < 16 * 64; i += 256)
        ws[i >> 6][i & 63] = w[i];
    for (int i = tid; i < TN * 64; i += 256) {
        int n = n0 + (i >> 6);
        xs[i >> 6][i & 63] = (n < N_NODES) ? x[(size_t)n * D + (i & 63)] : 0.f;
    }
    __syncthreads();

    // side-product: bf16 copy of the tile, coalesced 2B stores
    for (int i = tid; i < TN * 64; i += 256) {
        int n = n0 + (i >> 6);
        if (n < N_NODES) xb[(size_t)n0 * D + i] = f2bf(xs[i >> 6][i & 63]);
    }

    int q = tid & 15, nl = tid >> 4;
    float acc = 0.f;
#pragma unroll
    for (int k = 0; k < 64; k += 4) {
        float4 a = *(const float4*)&xs[nl][k];
        float4 b = *(const float4*)&ws[q][k];
        acc += a.x * b.x + a.y * b.y + a.z * b.z + a.w * b.w;
    }
    int n = n0 + nl;
    if (n < N_NODES) {
        int r = q >> 1;
        if ((q & 1) == 0) Dn[n * 8 + r] = acc;
        else              Sr[n * 8 + r] = acc;
    }
}

// ---------------------------------------------------------------------------
// K2: degree histogram that keeps the rank (only atomic pass).
// ---------------------------------------------------------------------------
__global__ void rank_kernel(const int* __restrict__ dst,
                            int* __restrict__ cnt, int* __restrict__ rank) {
    int e = blockIdx.x * blockDim.x + threadIdx.x;
    if (e < N_EDGES) rank[e] = atomicAdd(&cnt[dst[e]], 1);
}

// ---------------------------------------------------------------------------
// K3a/b/c: exclusive scan of cnt -> row_ptr
// ---------------------------------------------------------------------------
__global__ __launch_bounds__(256) void scanA(const int* __restrict__ cnt,
                                             int* __restrict__ excl,
                                             int* __restrict__ partial) {
    __shared__ int s[256];
    int t = threadIdx.x;
    int i = blockIdx.x * 256 + t;
    int v = (i < N_NODES) ? cnt[i] : 0;
    s[t] = v;
    __syncthreads();
    for (int off = 1; off < 256; off <<= 1) {
        int add = (t >= off) ? s[t - off] : 0;
        __syncthreads();
        s[t] += add;
        __syncthreads();
    }
    if (i < N_NODES) excl[i] = s[t] - v;
    if (t == 255) partial[blockIdx.x] = s[255];
}

__global__ __launch_bounds__(256) void scanB(int* __restrict__ partial) {
    __shared__ int s[256];
    int t = threadIdx.x;
    int v = (t < NB_SCAN) ? partial[t] : 0;
    s[t] = v;
    __syncthreads();
    for (int off = 1; off < 256; off <<= 1) {
        int add = (t >= off) ? s[t - off] : 0;
        __syncthreads();
        s[t] += add;
        __syncthreads();
    }
    if (t < NB_SCAN) partial[t] = s[t] - v;
}

__global__ __launch_bounds__(256) void scanC(const int* __restrict__ excl,
                                             const int* __restrict__ partial,
                                             int* __restrict__ row_ptr) {
    int i = blockIdx.x * 256 + threadIdx.x;
    if (i < N_NODES) row_ptr[i] = excl[i] + partial[i >> 8];
    if (i == N_NODES) row_ptr[N_NODES] = N_EDGES;
}

// ---------------------------------------------------------------------------
// K4: scatter edges into CSR order with gate precomputed. No atomics.
// ---------------------------------------------------------------------------
__global__ void scatter_kernel(const int* __restrict__ src, const int* __restrict__ dst,
                               const int* __restrict__ rel, const int* __restrict__ rank,
                               const int* __restrict__ row_ptr,
                               const float* __restrict__ Dn, const float* __restrict__ Sr,
                               float2* __restrict__ epack) {
    int e = blockIdx.x * blockDim.x + threadIdx.x;
    if (e >= N_EDGES) return;
    int s = src[e], d = dst[e], r = rel[e];
    float logit = Dn[d * 8 + r] + Sr[s * 8 + r];
    float gate = 1.0f / (1.0f + __expf(-logit));
    int pos = row_ptr[d] + rank[e];
    float2 v; v.x = gate; v.y = __int_as_float(s);
    epack[pos] = v;
}

// ---------------------------------------------------------------------------
// K5: aggregation, bf16 gather path. Wave = 4 edge-slots x 16 lanes; lane
// owns 4 dims via one 8B uint2 load (16 lanes x 8B = full 128B bf16 row).
// R8 showed agg is line/byte-bound: bf16 halves both bytes and 64B lines
// per edge, and the 6.4MB xb working set ~fits per-XCD L2.
// ---------------------------------------------------------------------------
__global__ __launch_bounds__(256) void agg_kernel(
    const unsigned short* __restrict__ xb,
    const int*   __restrict__ row_ptr,
    const float2* __restrict__ epack,
    float* __restrict__ agg)           // (N_NODES, 64) normalized
{
    int n    = (blockIdx.x * blockDim.x + threadIdx.x) >> 6;
    int lane = threadIdx.x & 63;
    if (n >= N_NODES) return;

    int sub = lane >> 4;      // edge slot 0..3
    int q   = lane & 15;      // dims 4q..4q+3
    int beg = row_ptr[n], end = row_ptr[n + 1];

    float ax = 0.f, ay = 0.f, az = 0.f, aw = 0.f;

    for (int base = beg; base < end; base += 8) {
        int e0 = base + sub;
        int e1 = base + 4 + sub;
        float g0 = 0.f, g1 = 0.f;
        int   s0 = 0,   s1 = 0;
        if (e0 < end) { float2 v = epack[e0]; g0 = v.x; s0 = __float_as_int(v.y); }
        if (e1 < end) { float2 v = epack[e1]; g1 = v.x; s1 = __float_as_int(v.y); }
        uint2 u0 = {0u, 0u}, u1 = {0u, 0u};
        if (e0 < end) u0 = *(const uint2*)&xb[(size_t)s0 * D + 4 * q];
        if (e1 < end) u1 = *(const uint2*)&xb[(size_t)s1 * D + 4 * q];
        ax += g0 * __uint_as_float(u0.x << 16);
        ay += g0 * __uint_as_float(u0.x & 0xFFFF0000u);
        az += g0 * __uint_as_float(u0.y << 16);
        aw += g0 * __uint_as_float(u0.y & 0xFFFF0000u);
        ax += g1 * __uint_as_float(u1.x << 16);
        ay += g1 * __uint_as_float(u1.x & 0xFFFF0000u);
        az += g1 * __uint_as_float(u1.y << 16);
        aw += g1 * __uint_as_float(u1.y & 0xFFFF0000u);
    }

    // reduce the 4 edge slots (lanes xor 16, xor 32)
#pragma unroll
    for (int off = 16; off <= 32; off <<= 1) {
        ax += __shfl_xor(ax, off, 64);
        ay += __shfl_xor(ay, off, 64);
        az += __shfl_xor(az, off, 64);
        aw += __shfl_xor(aw, off, 64);
    }

    if (sub == 0) {
        float inv = 1.0f / fmaxf((float)(end - beg), 1.0f);
        float4 r; r.x = ax * inv; r.y = ay * inv; r.z = az * inv; r.w = aw * inv;
        *(float4*)&agg[(size_t)n * D + 4 * q] = r;
    }
}

// ---------------------------------------------------------------------------
// K6: out = leaky_relu([x, agg] @ W_lin^T + b). Block = 256 thr, 32 nodes.
// ---------------------------------------------------------------------------
__global__ __launch_bounds__(256, 4) void lin_kernel(
    const float* __restrict__ x,
    const float* __restrict__ agg,
    const float* __restrict__ W_lin,
    const float* __restrict__ b_lin,
    float* __restrict__ out)
{
    __shared__ float c_lds[NODES_PER_BLK][CSTRIDE];
    __shared__ float W_lds[64][CSTRIDE];
    __shared__ float b_lds[64];

    int tid  = threadIdx.x;
    int wid  = tid >> 6;
    int lane = tid & 63;
    int n0   = blockIdx.x * NODES_PER_BLK;

    for (int i = tid; i < 64 * 128; i += 256)
        W_lds[i >> 7][i & 127] = W_lin[i];
    if (tid < 64) b_lds[tid] = b_lin[tid];

#pragma unroll
    for (int it = 0; it < NODES_PER_BLK / 4; ++it) {
        int nl = wid * (NODES_PER_BLK / 4) + it;
        int n  = n0 + nl;
        if (n < N_NODES) {
            c_lds[nl][lane]      = x[(size_t)n * D + lane];
            c_lds[nl][64 + lane] = agg[(size_t)n * D + lane];
        } else {
            c_lds[nl][lane] = 0.f;
            c_lds[nl][64 + lane] = 0.f;
        }
    }
    __syncthreads();

    int tx = tid & 15, ty = tid >> 4;
    float acc[2][4];
#pragma unroll
    for (int i = 0; i < 2; ++i)
#pragma unroll
        for (int jj = 0; jj < 4; ++jj) acc[i][jj] = b_lds[tx + 16 * jj];

#pragma unroll 2
    for (int k = 0; k < 128; k += 4) {
        float4 cv[2], wv[4];
        cv[0] = *(const float4*)&c_lds[ty][k];
        cv[1] = *(const float4*)&c_lds[ty + 16][k];
#pragma unroll
        for (int jj = 0; jj < 4; ++jj)
            wv[jj] = *(const float4*)&W_lds[tx + 16 * jj][k];
#pragma unroll
        for (int i = 0; i < 2; ++i)
#pragma unroll
            for (int jj = 0; jj < 4; ++jj)
                acc[i][jj] += cv[i].x * wv[jj].x + cv[i].y * wv[jj].y
                            + cv[i].z * wv[jj].z + cv[i].w * wv[jj].w;
    }

#pragma unroll
    for (int i = 0; i < 2; ++i) {
        int n = n0 + ty + 16 * i;
        if (n < N_NODES) {
#pragma unroll
            for (int jj = 0; jj < 4; ++jj) {
                float v = acc[i][jj];
                out[(size_t)n * D + tx + 16 * jj] = (v > 0.f) ? v : 0.01f * v;
            }
        }
    }
}

// ---------------------------------------------------------------------------
extern "C" void kernel_launch(void* const* d_in, const int* in_sizes, int n_in,
                              void* d_out, int out_size, void* d_ws, size_t ws_size,
                              hipStream_t stream) {
    const float* x     = (const float*)d_in[0];
    const int*   src   = (const int*)  d_in[1];
    const int*   dst   = (const int*)  d_in[2];
    const int*   rel   = (const int*)  d_in[3];
    const float* W_r   = (const float*)d_in[4];
    const float* W_lin = (const float*)d_in[5];
    const float* b_lin = (const float*)d_in[6];
    float* out = (float*)d_out;

    char* p = (char*)d_ws;
    float*  w       = (float*)p;                p += 4096;
    float*  Dn      = (float*)p;                p += (size_t)N_NODES * 8 * 4;   // 1.6 MB
    float*  Sr      = (float*)p;                p += (size_t)N_NODES * 8 * 4;   // 1.6 MB
    int*    cnt     = (int*)p;                  p += (size_t)N_NODES * 4;
    int*    excl    = (int*)p;                  p += (size_t)N_NODES * 4;
    int*    row_ptr = (int*)p;                  p += (size_t)(N_NODES + 64) * 4;
    int*    partial = (int*)p;                  p += 1024;
    int*    rank    = (int*)p;                  p += (size_t)N_EDGES * 4;       // 3.2 MB
    float*  agg     = (float*)p;                p += (size_t)N_NODES * D * 4;   // 12.8 MB
    float2* epack   = (float2*)p;               p += (size_t)N_EDGES * 8;       // 6.4 MB
    unsigned short* xb = (unsigned short*)p;    p += (size_t)N_NODES * D * 2;   // 6.4 MB

    hipMemsetAsync(cnt, 0, (size_t)N_NODES * sizeof(int), stream);

    wprep_kernel<<<4, 256, 0, stream>>>(W_r, w);
    tables_kernel<<<(N_NODES + TN - 1) / TN, 256, 0, stream>>>(x, w, Dn, Sr, xb);
    rank_kernel<<<(N_EDGES + 255) / 256, 256, 0, stream>>>(dst, cnt, rank);
    scanA<<<NB_SCAN, 256, 0, stream>>>(cnt, excl, partial);
    scanB<<<1, 256, 0, stream>>>(partial);
    scanC<<<NB_SCAN, 256, 0, stream>>>(excl, partial, row_ptr);
    scatter_kernel<<<(N_EDGES + 255) / 256, 256, 0, stream>>>(src, dst, rel, rank, row_ptr,
                                                              Dn, Sr, epack);
    agg_kernel<<<(N_NODES * 64 + 255) / 256, 256, 0, stream>>>(xb, row_ptr, epack, agg);
    lin_kernel<<<(N_NODES + NODES_PER_BLK - 1) / NODES_PER_BLK, 256, 0, stream>>>(
        x, agg, W_lin, b_lin, out);
}